// Round 9
// baseline (352.673 us; speedup 1.0000x reference)
//
#include <hip/hip_runtime.h>
#include <hip/hip_bf16.h>
#include <stdint.h>

// MultiHeadDiffAttention — R9.
// diffattn: single-barrier double-buffered K/V staging (barriers/iter 2->1,
// stage-write moved off the critical path), exp2-domain softmax (native v_exp).
// GEMMs: BK 32->64 (proven m97 874-912 TF geometry).
// B=2, T=2048, C=1024, H=16, HS=64.

#define T_SEQ 2048

typedef unsigned short u16;
typedef __attribute__((ext_vector_type(8))) short short8;
typedef __attribute__((ext_vector_type(4))) float f32x4;
typedef __attribute__((ext_vector_type(16))) float f32x16;

#define LAMBDA_INIT 0.35550906759096926f
#define ONE_MINUS_LI 0.6444909324090307f
#define SM_SCALE 0.125f
#define LOG2E 1.44269504f

__device__ __forceinline__ u16 f2bf(float f) {
  uint32_t u = __float_as_uint(f);
  return (u16)((u + 0x7FFFu + ((u >> 16) & 1u)) >> 16);
}
__device__ __forceinline__ float b2f(u16 u) {
  return __uint_as_float(((uint32_t)u) << 16);
}
__device__ __forceinline__ short8 ld8(const u16* p) {
  return *reinterpret_cast<const short8*>(p);
}
__device__ __forceinline__ void st8(u16* p, short8 v) {
  *reinterpret_cast<short8*>(p) = v;
}
__device__ __forceinline__ f32x4 mfma16(short8 a, short8 b, f32x4 c) {
  return __builtin_amdgcn_mfma_f32_16x16x32_bf16(a, b, c, 0, 0, 0);
}
__device__ __forceinline__ f32x16 mfma32(short8 a, short8 b, f32x16 c) {
  return __builtin_amdgcn_mfma_f32_32x32x16_bf16(a, b, c, 0, 0, 0);
}
__device__ __forceinline__ uint32_t cvtpk(float lo, float hi_) {
  uint32_t r;
  asm("v_cvt_pk_bf16_f32 %0, %1, %2" : "=v"(r) : "v"(lo), "v"(hi_));
  return r;
}

// ---------------- elementwise f32 -> bf16 ----------------
__global__ __launch_bounds__(256) void cvt_bf16(const float* __restrict__ in,
                                                u16* __restrict__ out, int n) {
  int i = (blockIdx.x * 256 + threadIdx.x) * 4;
  if (i >= n) return;
  float4 f = *reinterpret_cast<const float4*>(in + i);
  union { u16 u[4]; uint2 v; } pk;
  pk.u[0] = f2bf(f.x); pk.u[1] = f2bf(f.y); pk.u[2] = f2bf(f.z); pk.u[3] = f2bf(f.w);
  *reinterpret_cast<uint2*>(out + i) = pk.v;
}

// ------------- transpose + convert: W[K][N] f32 -> WT[N][K] bf16 -------------
__global__ __launch_bounds__(256) void tcvt(const float* __restrict__ W,
                                            u16* __restrict__ WT,
                                            int K, int N, int outRowOff) {
  __shared__ float tile[32][33];
  int n0 = blockIdx.x * 32, k0 = blockIdx.y * 32;
  int tx = threadIdx.x & 31, ty = threadIdx.x >> 5;  // ty 0..7
#pragma unroll
  for (int p = 0; p < 4; ++p)
    tile[ty + 8 * p][tx] = W[(size_t)(k0 + ty + 8 * p) * N + n0 + tx];
  __syncthreads();
#pragma unroll
  for (int p = 0; p < 4; ++p)
    WT[(size_t)(outRowOff + n0 + ty + 8 * p) * K + k0 + tx] = f2bf(tile[tx][ty + 8 * p]);
}

// ---------------- concat two 1024-float biases ----------------
__global__ __launch_bounds__(256) void bias_concat(const float* __restrict__ b1,
                                                   const float* __restrict__ b2,
                                                   float* __restrict__ out) {
  int i = blockIdx.x * 256 + threadIdx.x;  // 0..2047
  out[i] = (i < 1024) ? b1[i] : b2[i - 1024];
}

// ---------------- GEMM: C[M][N] = A[M][K] @ BT[N][K]^T + bias ----------------
// m97 geometry: 128x128 tile, BK=64, 4 waves, global_load_lds width 16.
// EPI 0: bf16 [M][N].  EPI 1: bf16 vvT ((b*2048+col)*2048 + t).  EPI 2: f32 [M][N].
#define BM 128
#define BN 128
#define BK 64

template <int EPI>
__global__ __launch_bounds__(256) void gemm_bt(const u16* __restrict__ A,
                                               const u16* __restrict__ BT,
                                               const float* __restrict__ bias,
                                               void* __restrict__ Cv,
                                               int M, int N, int K) {
  __shared__ __align__(16) u16 As[BM * BK];
  __shared__ __align__(16) u16 Bs[BN * BK];
  int t = threadIdx.x;
  int w = t >> 6, l = t & 63;
  int g = l >> 4, c16 = l & 15;
  int wr = w >> 1, wc = w & 1;
  size_t gm = (size_t)blockIdx.y * BM, gn = (size_t)blockIdx.x * BN;

  f32x4 acc[4][4] = {};

  int srow = l >> 3;       // 0..7 (8 lanes per row, 8 elems each)
  int scol = (l & 7) * 8;  // 0..56
  const u16* Ag = A + (gm + w * 32 + srow) * (size_t)K + scol;
  const u16* Bg = BT + (gn + w * 32 + srow) * (size_t)K + scol;

  for (int kt = 0; kt < K; kt += BK) {
    __syncthreads();
#pragma unroll
    for (int c = 0; c < 4; ++c) {
      __builtin_amdgcn_global_load_lds(
          (const __attribute__((address_space(1))) void*)(Ag + (size_t)(c * 8) * K + kt),
          (__attribute__((address_space(3))) void*)&As[(w * 32 + c * 8) * BK], 16, 0, 0);
      __builtin_amdgcn_global_load_lds(
          (const __attribute__((address_space(1))) void*)(Bg + (size_t)(c * 8) * K + kt),
          (__attribute__((address_space(3))) void*)&Bs[(w * 32 + c * 8) * BK], 16, 0, 0);
    }
    __syncthreads();
#pragma unroll
    for (int kk = 0; kk < 2; ++kk) {
      short8 af[4], bf[4];
#pragma unroll
      for (int m = 0; m < 4; ++m)
        af[m] = *reinterpret_cast<const short8*>(
            &As[(wr * 64 + m * 16 + c16) * BK + kk * 32 + g * 8]);
#pragma unroll
      for (int n = 0; n < 4; ++n)
        bf[n] = *reinterpret_cast<const short8*>(
            &Bs[(wc * 64 + n * 16 + c16) * BK + kk * 32 + g * 8]);
#pragma unroll
      for (int m = 0; m < 4; ++m)
#pragma unroll
        for (int n = 0; n < 4; ++n)
          acc[m][n] = mfma16(af[m], bf[n], acc[m][n]);
    }
  }

#pragma unroll
  for (int m = 0; m < 4; ++m)
#pragma unroll
    for (int n = 0; n < 4; ++n) {
      int row0 = (int)gm + wr * 64 + m * 16 + g * 4;
      int col = (int)gn + wc * 64 + n * 16 + c16;
      float bz = bias[col];
      if (EPI == 0) {
        u16* C = (u16*)Cv;
#pragma unroll
        for (int r = 0; r < 4; ++r)
          C[(size_t)(row0 + r) * N + col] = f2bf(acc[m][n][r] + bz);
      } else if (EPI == 1) {
        u16* C = (u16*)Cv;
        int bb = row0 >> 11, tt = row0 & 2047;
        union { u16 u[4]; uint2 v; } pk;
#pragma unroll
        for (int r = 0; r < 4; ++r) pk.u[r] = f2bf(acc[m][n][r] + bz);
        *reinterpret_cast<uint2*>(&C[((size_t)(bb * 2048 + col)) * 2048 + tt]) = pk.v;
      } else {
        float* C = (float*)Cv;
#pragma unroll
        for (int r = 0; r < 4; ++r)
          C[(size_t)(row0 + r) * N + col] = acc[m][n][r] + bz;
      }
    }
}

// ---------------- differential flash attention + fused LN (32x32 swapped) ----
// grid (T/64, B*H), block 256 = 4 waves = 2 pairs. Pair p covers q-rows
// [bx*64 + p*32, +32); wave stream s handles attention stream s+1.
// Double-buffered LDS staging, ONE barrier per 32-key tile.
#define KROW 72   // K row: 64 elems + pad
#define VROW 40   // V row: 32 elems + pad
#define YROW 72
__global__ __launch_bounds__(256, 4) void diffattn(
    const u16* __restrict__ q1q2, const u16* __restrict__ k1k2,
    const u16* __restrict__ vvT, const int* __restrict__ mask,
    const float* __restrict__ lq1, const float* __restrict__ lk1,
    const float* __restrict__ lq2, const float* __restrict__ lk2,
    const float* __restrict__ lnw, const float* __restrict__ lnb,
    u16* __restrict__ yout) {
  // per buffer: Ks [2][32][KROW]=4608 + Vs [128][VROW]=5120 = 9728 elems
  __shared__ __align__(16) u16 smem[2][9728];

  int tid = threadIdx.x;
  int w = tid >> 6, l = tid & 63;
  int q = l & 31, hi = l >> 5;
  int pair = w >> 1, stream = w & 1;
  int bh = blockIdx.y, b = bh >> 4, h = bh & 15;
  int qr0 = blockIdx.x * 64 + pair * 32;

  // lambda
  float lm1 = lq1[h * 64 + l] * lk1[h * 64 + l];
  float lm2 = lq2[h * 64 + l] * lk2[h * 64 + l];
#pragma unroll
  for (int o = 32; o; o >>= 1) {
    lm1 += __shfl_xor(lm1, o);
    lm2 += __shfl_xor(lm2, o);
  }
  float lam = __expf(lm1) - __expf(lm2) + LAMBDA_INIT;

  int soff = stream * 1024;
  const u16* qrow = q1q2 + (size_t)(b * T_SEQ + qr0 + q) * 2048 + h * 64 + soff + hi * 8;
  short8 qf[4];
#pragma unroll
  for (int c = 0; c < 4; ++c) qf[c] = ld8(qrow + c * 16);

  // softmax in log2 domain: fold log2e into the scale
  float scale = (mask[b * T_SEQ + qr0 + q] == 0) ? 0.f : (SM_SCALE * LOG2E);

  float M = -INFINITY, L = 0.f;
  f32x16 acc[4] = {};

  // staging assignments (per thread: 2 K units + 2 V units of 16B)
  int ku = tid * 2;
  int krow = ku >> 3, kslot = ku & 7;
  int kstream = krow >> 5, kkey = krow & 31;
  const u16* srcK = k1k2 + (size_t)(b * T_SEQ + kkey) * 2048 + h * 64 + kstream * 1024 + kslot * 8;
  int dK = (kstream * 32 + kkey) * KROW + kslot * 8;
  int vd = tid >> 1, vslot = (tid & 1) * 2;
  const u16* srcV = vvT + ((size_t)(b * 16 + h) * 128 + vd) * 2048 + vslot * 8;
  int dV = 4608 + vd * VROW + vslot * 8;

  // prologue: stage tile 0 into buf 0
  {
    short8 k0 = ld8(srcK), k1v = ld8(srcK + 8);
    short8 v0 = ld8(srcV), v1 = ld8(srcV + 8);
    st8(&smem[0][dK], k0); st8(&smem[0][dK + 8], k1v);
    st8(&smem[0][dV], v0); st8(&smem[0][dV + 8], v1);
  }
  __syncthreads();

  short8 kr0, kr1, vr0, vr1;
  for (int kt = 0; kt < T_SEQ; kt += 32) {
    int cur = (kt >> 5) & 1;
    bool more = (kt + 32 < T_SEQ);
    if (more) {  // issue next tile's global loads (hidden under compute)
      const u16* nk = srcK + (size_t)(kt + 32) * 2048;
      kr0 = ld8(nk); kr1 = ld8(nk + 8);
      const u16* nv = srcV + (kt + 32);
      vr0 = ld8(nv); vr1 = ld8(nv + 8);
    }

    const u16* Ksm = &smem[cur][0];
    const u16* Vsm = &smem[cur][4608];

    // K frags from LDS
    const u16* kbase = &Ksm[(stream * 32 + q) * KROW + hi * 8];
    short8 kf[4];
#pragma unroll
    for (int c = 0; c < 4; ++c) kf[c] = ld8(kbase + c * 16);

    f32x16 s = {};
#pragma unroll
    for (int c = 0; c < 4; ++c) s = mfma32(kf[c], qf[c], s);

    float x[16];
#pragma unroll
    for (int r = 0; r < 16; ++r) x[r] = s[r] * scale;

    float t8[8], t4[4];
#pragma unroll
    for (int i = 0; i < 8; ++i) t8[i] = fmaxf(x[i], x[i + 8]);
#pragma unroll
    for (int i = 0; i < 4; ++i) t4[i] = fmaxf(t8[i], t8[i + 4]);
    float tm = fmaxf(fmaxf(t4[0], t4[1]), fmaxf(t4[2], t4[3]));
    tm = fmaxf(tm, __shfl_xor(tm, 32));

    // defer-max (log2 units: 11.5 ~ e^8)
    if (!__all(tm - M <= 11.5f)) {
      float Mn = fmaxf(M, tm);
      float a = exp2f(M - Mn);
      L *= a;
#pragma unroll
      for (int d = 0; d < 4; ++d) acc[d] *= a;
      M = Mn;
    }

    float p[16];
#pragma unroll
    for (int r = 0; r < 16; ++r) p[r] = exp2f(x[r] - M);
    float s8[8], s4[4];
#pragma unroll
    for (int i = 0; i < 8; ++i) s8[i] = p[i] + p[i + 8];
#pragma unroll
    for (int i = 0; i < 4; ++i) s4[i] = s8[i] + s8[i + 4];
    float ps = (s4[0] + s4[1]) + (s4[2] + s4[3]);
    ps += __shfl_xor(ps, 32);
    L += ps;

    // P^T B-frags in-register
    uint32_t a1 = cvtpk(p[0], p[1]), a2 = cvtpk(p[2], p[3]);
    uint32_t b1 = cvtpk(p[4], p[5]), b2 = cvtpk(p[6], p[7]);
    uint32_t c1 = cvtpk(p[8], p[9]), c2 = cvtpk(p[10], p[11]);
    uint32_t d1 = cvtpk(p[12], p[13]), d2 = cvtpk(p[14], p[15]);
    uint32_t sa1 = (uint32_t)__shfl_xor((int)a1, 32), sa2 = (uint32_t)__shfl_xor((int)a2, 32);
    uint32_t sb1 = (uint32_t)__shfl_xor((int)b1, 32), sb2 = (uint32_t)__shfl_xor((int)b2, 32);
    uint32_t sc1 = (uint32_t)__shfl_xor((int)c1, 32), sc2 = (uint32_t)__shfl_xor((int)c2, 32);
    uint32_t sd1 = (uint32_t)__shfl_xor((int)d1, 32), sd2 = (uint32_t)__shfl_xor((int)d2, 32);
    union { uint32_t u[4]; short8 s8v; } pu0, pu1;
    pu0.u[0] = hi ? sb1 : a1;  pu0.u[1] = hi ? sb2 : a2;
    pu0.u[2] = hi ? b1 : sa1;  pu0.u[3] = hi ? b2 : sa2;
    pu1.u[0] = hi ? sd1 : c1;  pu1.u[1] = hi ? sd2 : c2;
    pu1.u[2] = hi ? d1 : sc1;  pu1.u[3] = hi ? d2 : sc2;
    short8 pf0 = pu0.s8v, pf1 = pu1.s8v;

#pragma unroll
    for (int d = 0; d < 4; ++d) {
      const u16* vb0 = &Vsm[(d * 32 + q) * VROW + hi * 8];
      short8 vf0 = ld8(vb0);
      short8 vf1 = ld8(vb0 + 16);
      acc[d] = mfma32(vf0, pf0, acc[d]);
      acc[d] = mfma32(vf1, pf1, acc[d]);
    }

    if (more) {  // write next tile into the other buffer (no barrier before)
      u16* nb = &smem[cur ^ 1][0];
      st8(&nb[dK], kr0); st8(&nb[dK + 8], kr1);
      st8(&nb[dV], vr0); st8(&nb[dV + 8], vr1);
    }
    __syncthreads();
  }

  float inv = 1.f / L;
  u16* Ysm = &smem[0][0];  // overlay (all staging dead)
  if (stream == 1) {
    u16* yrow = &Ysm[(pair * 64 + l) * YROW];
#pragma unroll
    for (int d = 0; d < 4; ++d) {
      union { uint32_t u[8]; short8 v[2]; } pk;
#pragma unroll
      for (int i = 0; i < 8; ++i)
        pk.u[i] = cvtpk(acc[d][2 * i] * inv, acc[d][2 * i + 1] * inv);
      st8(yrow + d * 16, pk.v[0]);
      st8(yrow + d * 16 + 8, pk.v[1]);
    }
  }
  __syncthreads();
  if (stream == 0) {
    const u16* yrow = &Ysm[(pair * 64 + l) * YROW];
    float y[4][16];
#pragma unroll
    for (int d = 0; d < 4; ++d) {
      short8 y2a = ld8(yrow + d * 16);
      short8 y2b = ld8(yrow + d * 16 + 8);
#pragma unroll
      for (int i = 0; i < 8; ++i) {
        y[d][i] = acc[d][i] * inv - lam * b2f((u16)y2a[i]);
        y[d][8 + i] = acc[d][8 + i] * inv - lam * b2f((u16)y2b[i]);
      }
    }
    float sm = 0.f;
#pragma unroll
    for (int d = 0; d < 4; ++d)
#pragma unroll
      for (int r = 0; r < 16; ++r) sm += y[d][r];
    sm += __shfl_xor(sm, 32);
    float u = sm * (1.f / 128.f);
    float var = 0.f;
#pragma unroll
    for (int d = 0; d < 4; ++d)
#pragma unroll
      for (int r = 0; r < 16; ++r) { float dd = y[d][r] - u; var += dd * dd; }
    var += __shfl_xor(var, 32);
    float rstd = rsqrtf(var * (1.f / 128.f) + 1e-12f);

    size_t orow = (size_t)(b * T_SEQ + qr0 + q) * 2048 + h * 128;
#pragma unroll
    for (int d = 0; d < 4; ++d)
#pragma unroll
      for (int rr = 0; rr < 4; ++rr) {
        int base = d * 32 + 8 * rr + 4 * hi;
        union { u16 u[4]; uint2 v; } o;
#pragma unroll
        for (int i = 0; i < 4; ++i) {
          float yv = (lnw[base + i] * ((y[d][rr * 4 + i] - u) * rstd) + lnb[base + i]) *
                     ONE_MINUS_LI;
          o.u[i] = f2bf(yv);
        }
        *reinterpret_cast<uint2*>(&yout[orow + base]) = o.v;
      }
  }
}

// ---------------- host ----------------
extern "C" void kernel_launch(void* const* d_in, const int* in_sizes, int n_in,
                              void* d_out, int out_size, void* d_ws, size_t ws_size,
                              hipStream_t stream) {
  (void)in_sizes; (void)n_in; (void)out_size; (void)ws_size;
  const float* q   = (const float*)d_in[0];
  const float* k   = (const float*)d_in[1];
  const float* v   = (const float*)d_in[2];
  const int* maskp = (const int*)d_in[3];
  const float* Wq1 = (const float*)d_in[4];
  const float* bq1 = (const float*)d_in[5];
  const float* Wq2 = (const float*)d_in[6];
  const float* bq2 = (const float*)d_in[7];
  const float* Wk1 = (const float*)d_in[8];
  const float* bk1 = (const float*)d_in[9];
  const float* Wk2 = (const float*)d_in[10];
  const float* bk2 = (const float*)d_in[11];
  const float* Wv  = (const float*)d_in[12];
  const float* bv  = (const float*)d_in[13];
  const float* Wc  = (const float*)d_in[14];
  const float* bc  = (const float*)d_in[15];
  const float* lnw = (const float*)d_in[16];
  const float* lnb = (const float*)d_in[17];
  const float* lq1 = (const float*)d_in[18];
  const float* lk1 = (const float*)d_in[19];
  const float* lq2 = (const float*)d_in[20];
  const float* lk2 = (const float*)d_in[21];

  char* ws = (char*)d_ws;
  u16* qb     = (u16*)(ws + 0);
  u16* kb     = (u16*)(ws + 8388608);
  u16* vb     = (u16*)(ws + 16777216);
  u16* Wq12T  = (u16*)(ws + 25165824);
  u16* Wk12T  = (u16*)(ws + 29360128);
  u16* WvT    = (u16*)(ws + 33554432);
  u16* WcT    = (u16*)(ws + 37748736);
  float* biasq = (float*)(ws + 41943040);
  float* biask = (float*)(ws + 41951232);
  u16* q1q2   = (u16*)(ws + 41959424);
  u16* k1k2   = (u16*)(ws + 58736640);
  u16* vvT    = (u16*)(ws + 75513856);
  u16* yb     = (u16*)(ws + 0);  // alias qb+kb (16MB; both dead before attention)

  const int NELEM = 2 * T_SEQ * 1024;  // 4,194,304

  cvt_bf16<<<4096, 256, 0, stream>>>(q, qb, NELEM);
  cvt_bf16<<<4096, 256, 0, stream>>>(k, kb, NELEM);
  cvt_bf16<<<4096, 256, 0, stream>>>(v, vb, NELEM);

  tcvt<<<dim3(32, 32), 256, 0, stream>>>(Wq1, Wq12T, 1024, 1024, 0);
  tcvt<<<dim3(32, 32), 256, 0, stream>>>(Wq2, Wq12T, 1024, 1024, 1024);
  tcvt<<<dim3(32, 32), 256, 0, stream>>>(Wk1, Wk12T, 1024, 1024, 0);
  tcvt<<<dim3(32, 32), 256, 0, stream>>>(Wk2, Wk12T, 1024, 1024, 1024);
  tcvt<<<dim3(64, 32), 256, 0, stream>>>(Wv, WvT, 1024, 2048, 0);
  tcvt<<<dim3(32, 64), 256, 0, stream>>>(Wc, WcT, 2048, 1024, 0);

  bias_concat<<<8, 256, 0, stream>>>(bq1, bq2, biasq);
  bias_concat<<<8, 256, 0, stream>>>(bk1, bk2, biask);

  gemm_bt<0><<<dim3(16, 32), 256, 0, stream>>>(qb, Wq12T, biasq, q1q2, 4096, 2048, 1024);
  gemm_bt<0><<<dim3(16, 32), 256, 0, stream>>>(kb, Wk12T, biask, k1k2, 4096, 2048, 1024);
  gemm_bt<1><<<dim3(16, 32), 256, 0, stream>>>(vb, WvT, bv, vvT, 4096, 2048, 1024);

  diffattn<<<dim3(32, 32), 256, 0, stream>>>(q1q2, k1k2, vvT, maskp,
                                             lq1, lk1, lq2, lk2, lnw, lnb, yb);

  gemm_bt<2><<<dim3(8, 32), 256, 0, stream>>>(yb, WcT, bc, d_out, 4096, 1024, 2048);
}

// Round 10
// 345.642 us; speedup vs baseline: 1.0203x; 1.0203x over previous
//
#include <hip/hip_runtime.h>
#include <hip/hip_bf16.h>
#include <stdint.h>

// MultiHeadDiffAttention — R10. R9 post-mortem: __launch_bounds__(256,4) capped
// VGPR at 64 -> acc spilled (20MB scratch round-trip, WRITE_SIZE 16->37MB).
// Single fix: restore (256,3). Keep R9's double-buffer single-barrier staging,
// exp2-domain softmax, and BK=64 m97-geometry GEMMs (they cut non-attn 162->134us).
// B=2, T=2048, C=1024, H=16, HS=64.

#define T_SEQ 2048

typedef unsigned short u16;
typedef __attribute__((ext_vector_type(8))) short short8;
typedef __attribute__((ext_vector_type(4))) float f32x4;
typedef __attribute__((ext_vector_type(16))) float f32x16;

#define LAMBDA_INIT 0.35550906759096926f
#define ONE_MINUS_LI 0.6444909324090307f
#define SM_SCALE 0.125f
#define LOG2E 1.44269504f

__device__ __forceinline__ u16 f2bf(float f) {
  uint32_t u = __float_as_uint(f);
  return (u16)((u + 0x7FFFu + ((u >> 16) & 1u)) >> 16);
}
__device__ __forceinline__ float b2f(u16 u) {
  return __uint_as_float(((uint32_t)u) << 16);
}
__device__ __forceinline__ short8 ld8(const u16* p) {
  return *reinterpret_cast<const short8*>(p);
}
__device__ __forceinline__ void st8(u16* p, short8 v) {
  *reinterpret_cast<short8*>(p) = v;
}
__device__ __forceinline__ f32x4 mfma16(short8 a, short8 b, f32x4 c) {
  return __builtin_amdgcn_mfma_f32_16x16x32_bf16(a, b, c, 0, 0, 0);
}
__device__ __forceinline__ f32x16 mfma32(short8 a, short8 b, f32x16 c) {
  return __builtin_amdgcn_mfma_f32_32x32x16_bf16(a, b, c, 0, 0, 0);
}
__device__ __forceinline__ uint32_t cvtpk(float lo, float hi_) {
  uint32_t r;
  asm("v_cvt_pk_bf16_f32 %0, %1, %2" : "=v"(r) : "v"(lo), "v"(hi_));
  return r;
}

// ---------------- elementwise f32 -> bf16 ----------------
__global__ __launch_bounds__(256) void cvt_bf16(const float* __restrict__ in,
                                                u16* __restrict__ out, int n) {
  int i = (blockIdx.x * 256 + threadIdx.x) * 4;
  if (i >= n) return;
  float4 f = *reinterpret_cast<const float4*>(in + i);
  union { u16 u[4]; uint2 v; } pk;
  pk.u[0] = f2bf(f.x); pk.u[1] = f2bf(f.y); pk.u[2] = f2bf(f.z); pk.u[3] = f2bf(f.w);
  *reinterpret_cast<uint2*>(out + i) = pk.v;
}

// ------------- transpose + convert: W[K][N] f32 -> WT[N][K] bf16 -------------
__global__ __launch_bounds__(256) void tcvt(const float* __restrict__ W,
                                            u16* __restrict__ WT,
                                            int K, int N, int outRowOff) {
  __shared__ float tile[32][33];
  int n0 = blockIdx.x * 32, k0 = blockIdx.y * 32;
  int tx = threadIdx.x & 31, ty = threadIdx.x >> 5;  // ty 0..7
#pragma unroll
  for (int p = 0; p < 4; ++p)
    tile[ty + 8 * p][tx] = W[(size_t)(k0 + ty + 8 * p) * N + n0 + tx];
  __syncthreads();
#pragma unroll
  for (int p = 0; p < 4; ++p)
    WT[(size_t)(outRowOff + n0 + ty + 8 * p) * K + k0 + tx] = f2bf(tile[tx][ty + 8 * p]);
}

// ---------------- concat two 1024-float biases ----------------
__global__ __launch_bounds__(256) void bias_concat(const float* __restrict__ b1,
                                                   const float* __restrict__ b2,
                                                   float* __restrict__ out) {
  int i = blockIdx.x * 256 + threadIdx.x;  // 0..2047
  out[i] = (i < 1024) ? b1[i] : b2[i - 1024];
}

// ---------------- GEMM: C[M][N] = A[M][K] @ BT[N][K]^T + bias ----------------
// m97 geometry: 128x128 tile, BK=64, 4 waves, global_load_lds width 16.
// EPI 0: bf16 [M][N].  EPI 1: bf16 vvT ((b*2048+col)*2048 + t).  EPI 2: f32 [M][N].
#define BM 128
#define BN 128
#define BK 64

template <int EPI>
__global__ __launch_bounds__(256) void gemm_bt(const u16* __restrict__ A,
                                               const u16* __restrict__ BT,
                                               const float* __restrict__ bias,
                                               void* __restrict__ Cv,
                                               int M, int N, int K) {
  __shared__ __align__(16) u16 As[BM * BK];
  __shared__ __align__(16) u16 Bs[BN * BK];
  int t = threadIdx.x;
  int w = t >> 6, l = t & 63;
  int g = l >> 4, c16 = l & 15;
  int wr = w >> 1, wc = w & 1;
  size_t gm = (size_t)blockIdx.y * BM, gn = (size_t)blockIdx.x * BN;

  f32x4 acc[4][4] = {};

  int srow = l >> 3;       // 0..7 (8 lanes per row, 8 elems each)
  int scol = (l & 7) * 8;  // 0..56
  const u16* Ag = A + (gm + w * 32 + srow) * (size_t)K + scol;
  const u16* Bg = BT + (gn + w * 32 + srow) * (size_t)K + scol;

  for (int kt = 0; kt < K; kt += BK) {
    __syncthreads();
#pragma unroll
    for (int c = 0; c < 4; ++c) {
      __builtin_amdgcn_global_load_lds(
          (const __attribute__((address_space(1))) void*)(Ag + (size_t)(c * 8) * K + kt),
          (__attribute__((address_space(3))) void*)&As[(w * 32 + c * 8) * BK], 16, 0, 0);
      __builtin_amdgcn_global_load_lds(
          (const __attribute__((address_space(1))) void*)(Bg + (size_t)(c * 8) * K + kt),
          (__attribute__((address_space(3))) void*)&Bs[(w * 32 + c * 8) * BK], 16, 0, 0);
    }
    __syncthreads();
#pragma unroll
    for (int kk = 0; kk < 2; ++kk) {
      short8 af[4], bf[4];
#pragma unroll
      for (int m = 0; m < 4; ++m)
        af[m] = *reinterpret_cast<const short8*>(
            &As[(wr * 64 + m * 16 + c16) * BK + kk * 32 + g * 8]);
#pragma unroll
      for (int n = 0; n < 4; ++n)
        bf[n] = *reinterpret_cast<const short8*>(
            &Bs[(wc * 64 + n * 16 + c16) * BK + kk * 32 + g * 8]);
#pragma unroll
      for (int m = 0; m < 4; ++m)
#pragma unroll
        for (int n = 0; n < 4; ++n)
          acc[m][n] = mfma16(af[m], bf[n], acc[m][n]);
    }
  }

#pragma unroll
  for (int m = 0; m < 4; ++m)
#pragma unroll
    for (int n = 0; n < 4; ++n) {
      int row0 = (int)gm + wr * 64 + m * 16 + g * 4;
      int col = (int)gn + wc * 64 + n * 16 + c16;
      float bz = bias[col];
      if (EPI == 0) {
        u16* C = (u16*)Cv;
#pragma unroll
        for (int r = 0; r < 4; ++r)
          C[(size_t)(row0 + r) * N + col] = f2bf(acc[m][n][r] + bz);
      } else if (EPI == 1) {
        u16* C = (u16*)Cv;
        int bb = row0 >> 11, tt = row0 & 2047;
        union { u16 u[4]; uint2 v; } pk;
#pragma unroll
        for (int r = 0; r < 4; ++r) pk.u[r] = f2bf(acc[m][n][r] + bz);
        *reinterpret_cast<uint2*>(&C[((size_t)(bb * 2048 + col)) * 2048 + tt]) = pk.v;
      } else {
        float* C = (float*)Cv;
#pragma unroll
        for (int r = 0; r < 4; ++r)
          C[(size_t)(row0 + r) * N + col] = acc[m][n][r] + bz;
      }
    }
}

// ---------------- differential flash attention + fused LN (32x32 swapped) ----
// grid (T/64, B*H), block 256 = 4 waves = 2 pairs. Pair p covers q-rows
// [bx*64 + p*32, +32); wave stream s handles attention stream s+1.
// Double-buffered LDS staging, ONE barrier per 32-key tile.
#define KROW 72   // K row: 64 elems + pad
#define VROW 40   // V row: 32 elems + pad
#define YROW 72
__global__ __launch_bounds__(256, 3) void diffattn(
    const u16* __restrict__ q1q2, const u16* __restrict__ k1k2,
    const u16* __restrict__ vvT, const int* __restrict__ mask,
    const float* __restrict__ lq1, const float* __restrict__ lk1,
    const float* __restrict__ lq2, const float* __restrict__ lk2,
    const float* __restrict__ lnw, const float* __restrict__ lnb,
    u16* __restrict__ yout) {
  // per buffer: Ks [2][32][KROW]=4608 + Vs [128][VROW]=5120 = 9728 elems
  __shared__ __align__(16) u16 smem[2][9728];

  int tid = threadIdx.x;
  int w = tid >> 6, l = tid & 63;
  int q = l & 31, hi = l >> 5;
  int pair = w >> 1, stream = w & 1;
  int bh = blockIdx.y, b = bh >> 4, h = bh & 15;
  int qr0 = blockIdx.x * 64 + pair * 32;

  // lambda
  float lm1 = lq1[h * 64 + l] * lk1[h * 64 + l];
  float lm2 = lq2[h * 64 + l] * lk2[h * 64 + l];
#pragma unroll
  for (int o = 32; o; o >>= 1) {
    lm1 += __shfl_xor(lm1, o);
    lm2 += __shfl_xor(lm2, o);
  }
  float lam = __expf(lm1) - __expf(lm2) + LAMBDA_INIT;

  int soff = stream * 1024;
  const u16* qrow = q1q2 + (size_t)(b * T_SEQ + qr0 + q) * 2048 + h * 64 + soff + hi * 8;
  short8 qf[4];
#pragma unroll
  for (int c = 0; c < 4; ++c) qf[c] = ld8(qrow + c * 16);

  // softmax in log2 domain: fold log2e into the scale
  float scale = (mask[b * T_SEQ + qr0 + q] == 0) ? 0.f : (SM_SCALE * LOG2E);

  float M = -INFINITY, L = 0.f;
  f32x16 acc[4] = {};

  // staging assignments (per thread: 2 K units + 2 V units of 16B)
  int ku = tid * 2;
  int krow = ku >> 3, kslot = ku & 7;
  int kstream = krow >> 5, kkey = krow & 31;
  const u16* srcK = k1k2 + (size_t)(b * T_SEQ + kkey) * 2048 + h * 64 + kstream * 1024 + kslot * 8;
  int dK = (kstream * 32 + kkey) * KROW + kslot * 8;
  int vd = tid >> 1, vslot = (tid & 1) * 2;
  const u16* srcV = vvT + ((size_t)(b * 16 + h) * 128 + vd) * 2048 + vslot * 8;
  int dV = 4608 + vd * VROW + vslot * 8;

  // prologue: stage tile 0 into buf 0
  {
    short8 k0 = ld8(srcK), k1v = ld8(srcK + 8);
    short8 v0 = ld8(srcV), v1 = ld8(srcV + 8);
    st8(&smem[0][dK], k0); st8(&smem[0][dK + 8], k1v);
    st8(&smem[0][dV], v0); st8(&smem[0][dV + 8], v1);
  }
  __syncthreads();

  short8 kr0, kr1, vr0, vr1;
  for (int kt = 0; kt < T_SEQ; kt += 32) {
    int cur = (kt >> 5) & 1;
    bool more = (kt + 32 < T_SEQ);
    if (more) {  // issue next tile's global loads (hidden under compute)
      const u16* nk = srcK + (size_t)(kt + 32) * 2048;
      kr0 = ld8(nk); kr1 = ld8(nk + 8);
      const u16* nv = srcV + (kt + 32);
      vr0 = ld8(nv); vr1 = ld8(nv + 8);
    }

    const u16* Ksm = &smem[cur][0];
    const u16* Vsm = &smem[cur][4608];

    // K frags from LDS
    const u16* kbase = &Ksm[(stream * 32 + q) * KROW + hi * 8];
    short8 kf[4];
#pragma unroll
    for (int c = 0; c < 4; ++c) kf[c] = ld8(kbase + c * 16);

    f32x16 s = {};
#pragma unroll
    for (int c = 0; c < 4; ++c) s = mfma32(kf[c], qf[c], s);

    float x[16];
#pragma unroll
    for (int r = 0; r < 16; ++r) x[r] = s[r] * scale;

    float t8[8], t4[4];
#pragma unroll
    for (int i = 0; i < 8; ++i) t8[i] = fmaxf(x[i], x[i + 8]);
#pragma unroll
    for (int i = 0; i < 4; ++i) t4[i] = fmaxf(t8[i], t8[i + 4]);
    float tm = fmaxf(fmaxf(t4[0], t4[1]), fmaxf(t4[2], t4[3]));
    tm = fmaxf(tm, __shfl_xor(tm, 32));

    // defer-max (log2 units: 11.5 ~ e^8)
    if (!__all(tm - M <= 11.5f)) {
      float Mn = fmaxf(M, tm);
      float a = exp2f(M - Mn);
      L *= a;
#pragma unroll
      for (int d = 0; d < 4; ++d) acc[d] *= a;
      M = Mn;
    }

    float p[16];
#pragma unroll
    for (int r = 0; r < 16; ++r) p[r] = exp2f(x[r] - M);
    float s8[8], s4[4];
#pragma unroll
    for (int i = 0; i < 8; ++i) s8[i] = p[i] + p[i + 8];
#pragma unroll
    for (int i = 0; i < 4; ++i) s4[i] = s8[i] + s8[i + 4];
    float ps = (s4[0] + s4[1]) + (s4[2] + s4[3]);
    ps += __shfl_xor(ps, 32);
    L += ps;

    // P^T B-frags in-register
    uint32_t a1 = cvtpk(p[0], p[1]), a2 = cvtpk(p[2], p[3]);
    uint32_t b1 = cvtpk(p[4], p[5]), b2 = cvtpk(p[6], p[7]);
    uint32_t c1 = cvtpk(p[8], p[9]), c2 = cvtpk(p[10], p[11]);
    uint32_t d1 = cvtpk(p[12], p[13]), d2 = cvtpk(p[14], p[15]);
    uint32_t sa1 = (uint32_t)__shfl_xor((int)a1, 32), sa2 = (uint32_t)__shfl_xor((int)a2, 32);
    uint32_t sb1 = (uint32_t)__shfl_xor((int)b1, 32), sb2 = (uint32_t)__shfl_xor((int)b2, 32);
    uint32_t sc1 = (uint32_t)__shfl_xor((int)c1, 32), sc2 = (uint32_t)__shfl_xor((int)c2, 32);
    uint32_t sd1 = (uint32_t)__shfl_xor((int)d1, 32), sd2 = (uint32_t)__shfl_xor((int)d2, 32);
    union { uint32_t u[4]; short8 s8v; } pu0, pu1;
    pu0.u[0] = hi ? sb1 : a1;  pu0.u[1] = hi ? sb2 : a2;
    pu0.u[2] = hi ? b1 : sa1;  pu0.u[3] = hi ? b2 : sa2;
    pu1.u[0] = hi ? sd1 : c1;  pu1.u[1] = hi ? sd2 : c2;
    pu1.u[2] = hi ? d1 : sc1;  pu1.u[3] = hi ? d2 : sc2;
    short8 pf0 = pu0.s8v, pf1 = pu1.s8v;

#pragma unroll
    for (int d = 0; d < 4; ++d) {
      const u16* vb0 = &Vsm[(d * 32 + q) * VROW + hi * 8];
      short8 vf0 = ld8(vb0);
      short8 vf1 = ld8(vb0 + 16);
      acc[d] = mfma32(vf0, pf0, acc[d]);
      acc[d] = mfma32(vf1, pf1, acc[d]);
    }

    if (more) {  // write next tile into the other buffer (no barrier before)
      u16* nb = &smem[cur ^ 1][0];
      st8(&nb[dK], kr0); st8(&nb[dK + 8], kr1);
      st8(&nb[dV], vr0); st8(&nb[dV + 8], vr1);
    }
    __syncthreads();
  }

  float inv = 1.f / L;
  u16* Ysm = &smem[0][0];  // overlay (all staging dead)
  if (stream == 1) {
    u16* yrow = &Ysm[(pair * 64 + l) * YROW];
#pragma unroll
    for (int d = 0; d < 4; ++d) {
      union { uint32_t u[8]; short8 v[2]; } pk;
#pragma unroll
      for (int i = 0; i < 8; ++i)
        pk.u[i] = cvtpk(acc[d][2 * i] * inv, acc[d][2 * i + 1] * inv);
      st8(yrow + d * 16, pk.v[0]);
      st8(yrow + d * 16 + 8, pk.v[1]);
    }
  }
  __syncthreads();
  if (stream == 0) {
    const u16* yrow = &Ysm[(pair * 64 + l) * YROW];
    float y[4][16];
#pragma unroll
    for (int d = 0; d < 4; ++d) {
      short8 y2a = ld8(yrow + d * 16);
      short8 y2b = ld8(yrow + d * 16 + 8);
#pragma unroll
      for (int i = 0; i < 8; ++i) {
        y[d][i] = acc[d][i] * inv - lam * b2f((u16)y2a[i]);
        y[d][8 + i] = acc[d][8 + i] * inv - lam * b2f((u16)y2b[i]);
      }
    }
    float sm = 0.f;
#pragma unroll
    for (int d = 0; d < 4; ++d)
#pragma unroll
      for (int r = 0; r < 16; ++r) sm += y[d][r];
    sm += __shfl_xor(sm, 32);
    float u = sm * (1.f / 128.f);
    float var = 0.f;
#pragma unroll
    for (int d = 0; d < 4; ++d)
#pragma unroll
      for (int r = 0; r < 16; ++r) { float dd = y[d][r] - u; var += dd * dd; }
    var += __shfl_xor(var, 32);
    float rstd = rsqrtf(var * (1.f / 128.f) + 1e-12f);

    size_t orow = (size_t)(b * T_SEQ + qr0 + q) * 2048 + h * 128;
#pragma unroll
    for (int d = 0; d < 4; ++d)
#pragma unroll
      for (int rr = 0; rr < 4; ++rr) {
        int base = d * 32 + 8 * rr + 4 * hi;
        union { u16 u[4]; uint2 v; } o;
#pragma unroll
        for (int i = 0; i < 4; ++i) {
          float yv = (lnw[base + i] * ((y[d][rr * 4 + i] - u) * rstd) + lnb[base + i]) *
                     ONE_MINUS_LI;
          o.u[i] = f2bf(yv);
        }
        *reinterpret_cast<uint2*>(&yout[orow + base]) = o.v;
      }
  }
}

// ---------------- host ----------------
extern "C" void kernel_launch(void* const* d_in, const int* in_sizes, int n_in,
                              void* d_out, int out_size, void* d_ws, size_t ws_size,
                              hipStream_t stream) {
  (void)in_sizes; (void)n_in; (void)out_size; (void)ws_size;
  const float* q   = (const float*)d_in[0];
  const float* k   = (const float*)d_in[1];
  const float* v   = (const float*)d_in[2];
  const int* maskp = (const int*)d_in[3];
  const float* Wq1 = (const float*)d_in[4];
  const float* bq1 = (const float*)d_in[5];
  const float* Wq2 = (const float*)d_in[6];
  const float* bq2 = (const float*)d_in[7];
  const float* Wk1 = (const float*)d_in[8];
  const float* bk1 = (const float*)d_in[9];
  const float* Wk2 = (const float*)d_in[10];
  const float* bk2 = (const float*)d_in[11];
  const float* Wv  = (const float*)d_in[12];
  const float* bv  = (const float*)d_in[13];
  const float* Wc  = (const float*)d_in[14];
  const float* bc  = (const float*)d_in[15];
  const float* lnw = (const float*)d_in[16];
  const float* lnb = (const float*)d_in[17];
  const float* lq1 = (const float*)d_in[18];
  const float* lk1 = (const float*)d_in[19];
  const float* lq2 = (const float*)d_in[20];
  const float* lk2 = (const float*)d_in[21];

  char* ws = (char*)d_ws;
  u16* qb     = (u16*)(ws + 0);
  u16* kb     = (u16*)(ws + 8388608);
  u16* vb     = (u16*)(ws + 16777216);
  u16* Wq12T  = (u16*)(ws + 25165824);
  u16* Wk12T  = (u16*)(ws + 29360128);
  u16* WvT    = (u16*)(ws + 33554432);
  u16* WcT    = (u16*)(ws + 37748736);
  float* biasq = (float*)(ws + 41943040);
  float* biask = (float*)(ws + 41951232);
  u16* q1q2   = (u16*)(ws + 41959424);
  u16* k1k2   = (u16*)(ws + 58736640);
  u16* vvT    = (u16*)(ws + 75513856);
  u16* yb     = (u16*)(ws + 0);  // alias qb+kb (16MB; both dead before attention)

  const int NELEM = 2 * T_SEQ * 1024;  // 4,194,304

  cvt_bf16<<<4096, 256, 0, stream>>>(q, qb, NELEM);
  cvt_bf16<<<4096, 256, 0, stream>>>(k, kb, NELEM);
  cvt_bf16<<<4096, 256, 0, stream>>>(v, vb, NELEM);

  tcvt<<<dim3(32, 32), 256, 0, stream>>>(Wq1, Wq12T, 1024, 1024, 0);
  tcvt<<<dim3(32, 32), 256, 0, stream>>>(Wq2, Wq12T, 1024, 1024, 1024);
  tcvt<<<dim3(32, 32), 256, 0, stream>>>(Wk1, Wk12T, 1024, 1024, 0);
  tcvt<<<dim3(32, 32), 256, 0, stream>>>(Wk2, Wk12T, 1024, 1024, 1024);
  tcvt<<<dim3(64, 32), 256, 0, stream>>>(Wv, WvT, 1024, 2048, 0);
  tcvt<<<dim3(32, 64), 256, 0, stream>>>(Wc, WcT, 2048, 1024, 0);

  bias_concat<<<8, 256, 0, stream>>>(bq1, bq2, biasq);
  bias_concat<<<8, 256, 0, stream>>>(bk1, bk2, biask);

  gemm_bt<0><<<dim3(16, 32), 256, 0, stream>>>(qb, Wq12T, biasq, q1q2, 4096, 2048, 1024);
  gemm_bt<0><<<dim3(16, 32), 256, 0, stream>>>(kb, Wk12T, biask, k1k2, 4096, 2048, 1024);
  gemm_bt<1><<<dim3(16, 32), 256, 0, stream>>>(vb, WvT, bv, vvT, 4096, 2048, 1024);

  diffattn<<<dim3(32, 32), 256, 0, stream>>>(q1q2, k1k2, vvT, maskp,
                                             lq1, lk1, lq2, lk2, lnw, lnb, yb);

  gemm_bt<2><<<dim3(8, 32), 256, 0, stream>>>(yb, WcT, bc, d_out, 4096, 1024, 2048);
}

// Round 11
// 330.009 us; speedup vs baseline: 1.0687x; 1.0474x over previous
//
#include <hip/hip_runtime.h>
#include <hip/hip_bf16.h>
#include <stdint.h>

// MultiHeadDiffAttention — R11. R8<->R10 A/B: dbuf single-barrier staging was
// SLOWER (compiler sinks prefetch to its same-iter use -> vmcnt stall on the
// barrier path). Revert diffattn to R8's proven 2-barrier staging; keep BK=64
// GEMMs. New: FMA-folded exp2 softmax (raw-max reduce), max3 max-tree, and
// XCD-aware block swizzle so same-(b,h) blocks share an XCD's L2 K/V.
// B=2, T=2048, C=1024, H=16, HS=64.

#define T_SEQ 2048

typedef unsigned short u16;
typedef __attribute__((ext_vector_type(8))) short short8;
typedef __attribute__((ext_vector_type(4))) float f32x4;
typedef __attribute__((ext_vector_type(16))) float f32x16;

#define LAMBDA_INIT 0.35550906759096926f
#define ONE_MINUS_LI 0.6444909324090307f
#define SM_SCALE 0.125f
#define LOG2E 1.44269504f

__device__ __forceinline__ u16 f2bf(float f) {
  uint32_t u = __float_as_uint(f);
  return (u16)((u + 0x7FFFu + ((u >> 16) & 1u)) >> 16);
}
__device__ __forceinline__ float b2f(u16 u) {
  return __uint_as_float(((uint32_t)u) << 16);
}
__device__ __forceinline__ short8 ld8(const u16* p) {
  return *reinterpret_cast<const short8*>(p);
}
__device__ __forceinline__ void st8(u16* p, short8 v) {
  *reinterpret_cast<short8*>(p) = v;
}
__device__ __forceinline__ f32x4 mfma16(short8 a, short8 b, f32x4 c) {
  return __builtin_amdgcn_mfma_f32_16x16x32_bf16(a, b, c, 0, 0, 0);
}
__device__ __forceinline__ f32x16 mfma32(short8 a, short8 b, f32x16 c) {
  return __builtin_amdgcn_mfma_f32_32x32x16_bf16(a, b, c, 0, 0, 0);
}
__device__ __forceinline__ uint32_t cvtpk(float lo, float hi_) {
  uint32_t r;
  asm("v_cvt_pk_bf16_f32 %0, %1, %2" : "=v"(r) : "v"(lo), "v"(hi_));
  return r;
}

// ---------------- elementwise f32 -> bf16 ----------------
__global__ __launch_bounds__(256) void cvt_bf16(const float* __restrict__ in,
                                                u16* __restrict__ out, int n) {
  int i = (blockIdx.x * 256 + threadIdx.x) * 4;
  if (i >= n) return;
  float4 f = *reinterpret_cast<const float4*>(in + i);
  union { u16 u[4]; uint2 v; } pk;
  pk.u[0] = f2bf(f.x); pk.u[1] = f2bf(f.y); pk.u[2] = f2bf(f.z); pk.u[3] = f2bf(f.w);
  *reinterpret_cast<uint2*>(out + i) = pk.v;
}

// ------------- transpose + convert: W[K][N] f32 -> WT[N][K] bf16 -------------
__global__ __launch_bounds__(256) void tcvt(const float* __restrict__ W,
                                            u16* __restrict__ WT,
                                            int K, int N, int outRowOff) {
  __shared__ float tile[32][33];
  int n0 = blockIdx.x * 32, k0 = blockIdx.y * 32;
  int tx = threadIdx.x & 31, ty = threadIdx.x >> 5;  // ty 0..7
#pragma unroll
  for (int p = 0; p < 4; ++p)
    tile[ty + 8 * p][tx] = W[(size_t)(k0 + ty + 8 * p) * N + n0 + tx];
  __syncthreads();
#pragma unroll
  for (int p = 0; p < 4; ++p)
    WT[(size_t)(outRowOff + n0 + ty + 8 * p) * K + k0 + tx] = f2bf(tile[tx][ty + 8 * p]);
}

// ---------------- concat two 1024-float biases ----------------
__global__ __launch_bounds__(256) void bias_concat(const float* __restrict__ b1,
                                                   const float* __restrict__ b2,
                                                   float* __restrict__ out) {
  int i = blockIdx.x * 256 + threadIdx.x;  // 0..2047
  out[i] = (i < 1024) ? b1[i] : b2[i - 1024];
}

// ---------------- GEMM: C[M][N] = A[M][K] @ BT[N][K]^T + bias ----------------
// m97 geometry: 128x128 tile, BK=64, 4 waves, global_load_lds width 16.
// EPI 0: bf16 [M][N].  EPI 1: bf16 vvT ((b*2048+col)*2048 + t).  EPI 2: f32 [M][N].
#define BM 128
#define BN 128
#define BK 64

template <int EPI>
__global__ __launch_bounds__(256) void gemm_bt(const u16* __restrict__ A,
                                               const u16* __restrict__ BT,
                                               const float* __restrict__ bias,
                                               void* __restrict__ Cv,
                                               int M, int N, int K) {
  __shared__ __align__(16) u16 As[BM * BK];
  __shared__ __align__(16) u16 Bs[BN * BK];
  int t = threadIdx.x;
  int w = t >> 6, l = t & 63;
  int g = l >> 4, c16 = l & 15;
  int wr = w >> 1, wc = w & 1;
  size_t gm = (size_t)blockIdx.y * BM, gn = (size_t)blockIdx.x * BN;

  f32x4 acc[4][4] = {};

  int srow = l >> 3;       // 0..7 (8 lanes per row, 8 elems each)
  int scol = (l & 7) * 8;  // 0..56
  const u16* Ag = A + (gm + w * 32 + srow) * (size_t)K + scol;
  const u16* Bg = BT + (gn + w * 32 + srow) * (size_t)K + scol;

  for (int kt = 0; kt < K; kt += BK) {
    __syncthreads();
#pragma unroll
    for (int c = 0; c < 4; ++c) {
      __builtin_amdgcn_global_load_lds(
          (const __attribute__((address_space(1))) void*)(Ag + (size_t)(c * 8) * K + kt),
          (__attribute__((address_space(3))) void*)&As[(w * 32 + c * 8) * BK], 16, 0, 0);
      __builtin_amdgcn_global_load_lds(
          (const __attribute__((address_space(1))) void*)(Bg + (size_t)(c * 8) * K + kt),
          (__attribute__((address_space(3))) void*)&Bs[(w * 32 + c * 8) * BK], 16, 0, 0);
    }
    __syncthreads();
#pragma unroll
    for (int kk = 0; kk < 2; ++kk) {
      short8 af[4], bf[4];
#pragma unroll
      for (int m = 0; m < 4; ++m)
        af[m] = *reinterpret_cast<const short8*>(
            &As[(wr * 64 + m * 16 + c16) * BK + kk * 32 + g * 8]);
#pragma unroll
      for (int n = 0; n < 4; ++n)
        bf[n] = *reinterpret_cast<const short8*>(
            &Bs[(wc * 64 + n * 16 + c16) * BK + kk * 32 + g * 8]);
#pragma unroll
      for (int m = 0; m < 4; ++m)
#pragma unroll
        for (int n = 0; n < 4; ++n)
          acc[m][n] = mfma16(af[m], bf[n], acc[m][n]);
    }
  }

#pragma unroll
  for (int m = 0; m < 4; ++m)
#pragma unroll
    for (int n = 0; n < 4; ++n) {
      int row0 = (int)gm + wr * 64 + m * 16 + g * 4;
      int col = (int)gn + wc * 64 + n * 16 + c16;
      float bz = bias[col];
      if (EPI == 0) {
        u16* C = (u16*)Cv;
#pragma unroll
        for (int r = 0; r < 4; ++r)
          C[(size_t)(row0 + r) * N + col] = f2bf(acc[m][n][r] + bz);
      } else if (EPI == 1) {
        u16* C = (u16*)Cv;
        int bb = row0 >> 11, tt = row0 & 2047;
        union { u16 u[4]; uint2 v; } pk;
#pragma unroll
        for (int r = 0; r < 4; ++r) pk.u[r] = f2bf(acc[m][n][r] + bz);
        *reinterpret_cast<uint2*>(&C[((size_t)(bb * 2048 + col)) * 2048 + tt]) = pk.v;
      } else {
        float* C = (float*)Cv;
#pragma unroll
        for (int r = 0; r < 4; ++r)
          C[(size_t)(row0 + r) * N + col] = acc[m][n][r] + bz;
      }
    }
}

// ---------------- differential flash attention + fused LN (32x32 swapped) ----
// grid 1024 (1D, XCD-swizzled), block 256 = 4 waves = 2 pairs.
// Pair p covers q-rows [xblk*64 + p*32, +32); wave stream s handles stream s+1.
// R8-proven 2-barrier staging (single buffer, prefetch issued after barrier-2).
#define KROW 72   // K row: 64 elems + pad
#define VROW 40   // V row: 32 elems + pad
#define YROW 72
__global__ __launch_bounds__(256, 3) void diffattn(
    const u16* __restrict__ q1q2, const u16* __restrict__ k1k2,
    const u16* __restrict__ vvT, const int* __restrict__ mask,
    const float* __restrict__ lq1, const float* __restrict__ lk1,
    const float* __restrict__ lq2, const float* __restrict__ lk2,
    const float* __restrict__ lnw, const float* __restrict__ lnb,
    u16* __restrict__ yout) {
  // Ks [2][32][KROW]=4608 + Vs [128][VROW]=5120 = 9728 elems; Ysm overlays.
  __shared__ __align__(16) u16 smem[9728];
  u16* Ksm = smem;
  u16* Vsm = smem + 4608;
  u16* Ysm = smem;

  int tid = threadIdx.x;
  int w = tid >> 6, l = tid & 63;
  int q = l & 31, hi = l >> 5;
  int pair = w >> 1, stream = w & 1;

  // XCD swizzle: consecutive dispatch ids round-robin XCDs; give each XCD a
  // contiguous run of q-blocks of the SAME (b,h) so K/V are L2-local.
  int id = blockIdx.x;            // 0..1023
  int j = id & 7, rest = id >> 3;
  int xblk = rest & 31, ygrp = rest >> 5;
  int bh = ygrp * 8 + j;
  int b = bh >> 4, h = bh & 15;
  int qr0 = xblk * 64 + pair * 32;

  // lambda
  float lm1 = lq1[h * 64 + l] * lk1[h * 64 + l];
  float lm2 = lq2[h * 64 + l] * lk2[h * 64 + l];
#pragma unroll
  for (int o = 32; o; o >>= 1) {
    lm1 += __shfl_xor(lm1, o);
    lm2 += __shfl_xor(lm2, o);
  }
  float lam = __expf(lm1) - __expf(lm2) + LAMBDA_INIT;

  int soff = stream * 1024;
  const u16* qrow = q1q2 + (size_t)(b * T_SEQ + qr0 + q) * 2048 + h * 64 + soff + hi * 8;
  short8 qf[4];
#pragma unroll
  for (int c = 0; c < 4; ++c) qf[c] = ld8(qrow + c * 16);

  // softmax in log2 domain; mask folds into scale (0 -> uniform softmax)
  float scale = (mask[b * T_SEQ + qr0 + q] == 0) ? 0.f : (SM_SCALE * LOG2E);

  float M = -INFINITY, L = 0.f;
  f32x16 acc[4] = {};

  // staging assignments (per thread: 2 K units + 2 V units of 16B)
  int ku = tid * 2;
  int krow = ku >> 3, kslot = ku & 7;
  int kstream = krow >> 5, kkey = krow & 31;
  const u16* srcK = k1k2 + (size_t)(b * T_SEQ + kkey) * 2048 + h * 64 + kstream * 1024 + kslot * 8;
  u16* dstK = &Ksm[(kstream * 32 + kkey) * KROW + kslot * 8];
  int vd = tid >> 1, vslot = (tid & 1) * 2;
  const u16* srcV = vvT + ((size_t)(b * 16 + h) * 128 + vd) * 2048 + vslot * 8;
  u16* dstV = &Vsm[vd * VROW + vslot * 8];

  short8 kr0 = ld8(srcK), kr1 = ld8(srcK + 8);
  short8 vr0 = ld8(srcV), vr1 = ld8(srcV + 8);

  for (int kt = 0; kt < T_SEQ; kt += 32) {
    __syncthreads();  // previous tile's reads complete
    st8(dstK, kr0); st8(dstK + 8, kr1);
    st8(dstV, vr0); st8(dstV + 8, vr1);
    __syncthreads();  // tile staged
    if (kt + 32 < T_SEQ) {  // prefetch next tile (consumed NEXT iter, across barrier)
      const u16* nk = srcK + (size_t)(kt + 32) * 2048;
      kr0 = ld8(nk); kr1 = ld8(nk + 8);
      const u16* nv = srcV + (kt + 32);
      vr0 = ld8(nv); vr1 = ld8(nv + 8);
    }

    // K frags from LDS
    const u16* kbase = &Ksm[(stream * 32 + q) * KROW + hi * 8];
    short8 kf[4];
#pragma unroll
    for (int c = 0; c < 4; ++c) kf[c] = ld8(kbase + c * 16);

    f32x16 s = {};
#pragma unroll
    for (int c = 0; c < 4; ++c) s = mfma32(kf[c], qf[c], s);

    // raw max (max3-shaped chain), then scale once
    float rm = fmaxf(fmaxf(s[0], s[1]), s[2]);
    rm = fmaxf(fmaxf(rm, s[3]), s[4]);
    rm = fmaxf(fmaxf(rm, s[5]), s[6]);
    rm = fmaxf(fmaxf(rm, s[7]), s[8]);
    rm = fmaxf(fmaxf(rm, s[9]), s[10]);
    rm = fmaxf(fmaxf(rm, s[11]), s[12]);
    rm = fmaxf(fmaxf(rm, s[13]), s[14]);
    rm = fmaxf(rm, s[15]);
    rm = fmaxf(rm, __shfl_xor(rm, 32));
    float tm = rm * scale;

    // defer-max (log2 units: 11.5 ~ e^8)
    if (!__all(tm - M <= 11.5f)) {
      float Mn = fmaxf(M, tm);
      float a = exp2f(M - Mn);
      L *= a;
#pragma unroll
      for (int d = 0; d < 4; ++d) acc[d] *= a;
      M = Mn;
    }

    // p = exp2(s*scale - M) via fused fma
    float p[16];
#pragma unroll
    for (int r = 0; r < 16; ++r) p[r] = exp2f(__builtin_fmaf(s[r], scale, -M));
    float s8[8], s4[4];
#pragma unroll
    for (int i = 0; i < 8; ++i) s8[i] = p[i] + p[i + 8];
#pragma unroll
    for (int i = 0; i < 4; ++i) s4[i] = s8[i] + s8[i + 4];
    float ps = (s4[0] + s4[1]) + (s4[2] + s4[3]);
    ps += __shfl_xor(ps, 32);
    L += ps;

    // P^T B-frags in-register
    uint32_t a1 = cvtpk(p[0], p[1]), a2 = cvtpk(p[2], p[3]);
    uint32_t b1 = cvtpk(p[4], p[5]), b2 = cvtpk(p[6], p[7]);
    uint32_t c1 = cvtpk(p[8], p[9]), c2 = cvtpk(p[10], p[11]);
    uint32_t d1 = cvtpk(p[12], p[13]), d2 = cvtpk(p[14], p[15]);
    uint32_t sa1 = (uint32_t)__shfl_xor((int)a1, 32), sa2 = (uint32_t)__shfl_xor((int)a2, 32);
    uint32_t sb1 = (uint32_t)__shfl_xor((int)b1, 32), sb2 = (uint32_t)__shfl_xor((int)b2, 32);
    uint32_t sc1 = (uint32_t)__shfl_xor((int)c1, 32), sc2 = (uint32_t)__shfl_xor((int)c2, 32);
    uint32_t sd1 = (uint32_t)__shfl_xor((int)d1, 32), sd2 = (uint32_t)__shfl_xor((int)d2, 32);
    union { uint32_t u[4]; short8 s8v; } pu0, pu1;
    pu0.u[0] = hi ? sb1 : a1;  pu0.u[1] = hi ? sb2 : a2;
    pu0.u[2] = hi ? b1 : sa1;  pu0.u[3] = hi ? b2 : sa2;
    pu1.u[0] = hi ? sd1 : c1;  pu1.u[1] = hi ? sd2 : c2;
    pu1.u[2] = hi ? d1 : sc1;  pu1.u[3] = hi ? d2 : sc2;
    short8 pf0 = pu0.s8v, pf1 = pu1.s8v;

#pragma unroll
    for (int d = 0; d < 4; ++d) {
      const u16* vb0 = &Vsm[(d * 32 + q) * VROW + hi * 8];
      short8 vf0 = ld8(vb0);
      short8 vf1 = ld8(vb0 + 16);
      acc[d] = mfma32(vf0, pf0, acc[d]);
      acc[d] = mfma32(vf1, pf1, acc[d]);
    }
  }

  float inv = 1.f / L;
  __syncthreads();  // staging dead -> Ysm overlay safe
  if (stream == 1) {
    u16* yrow = &Ysm[(pair * 64 + l) * YROW];
#pragma unroll
    for (int d = 0; d < 4; ++d) {
      union { uint32_t u[8]; short8 v[2]; } pk;
#pragma unroll
      for (int i = 0; i < 8; ++i)
        pk.u[i] = cvtpk(acc[d][2 * i] * inv, acc[d][2 * i + 1] * inv);
      st8(yrow + d * 16, pk.v[0]);
      st8(yrow + d * 16 + 8, pk.v[1]);
    }
  }
  __syncthreads();
  if (stream == 0) {
    const u16* yrow = &Ysm[(pair * 64 + l) * YROW];
    float y[4][16];
#pragma unroll
    for (int d = 0; d < 4; ++d) {
      short8 y2a = ld8(yrow + d * 16);
      short8 y2b = ld8(yrow + d * 16 + 8);
#pragma unroll
      for (int i = 0; i < 8; ++i) {
        y[d][i] = acc[d][i] * inv - lam * b2f((u16)y2a[i]);
        y[d][8 + i] = acc[d][8 + i] * inv - lam * b2f((u16)y2b[i]);
      }
    }
    float sm = 0.f;
#pragma unroll
    for (int d = 0; d < 4; ++d)
#pragma unroll
      for (int r = 0; r < 16; ++r) sm += y[d][r];
    sm += __shfl_xor(sm, 32);
    float u = sm * (1.f / 128.f);
    float var = 0.f;
#pragma unroll
    for (int d = 0; d < 4; ++d)
#pragma unroll
      for (int r = 0; r < 16; ++r) { float dd = y[d][r] - u; var += dd * dd; }
    var += __shfl_xor(var, 32);
    float rstd = rsqrtf(var * (1.f / 128.f) + 1e-12f);

    size_t orow = (size_t)(b * T_SEQ + qr0 + q) * 2048 + h * 128;
#pragma unroll
    for (int d = 0; d < 4; ++d)
#pragma unroll
      for (int rr = 0; rr < 4; ++rr) {
        int base = d * 32 + 8 * rr + 4 * hi;
        union { u16 u[4]; uint2 v; } o;
#pragma unroll
        for (int i = 0; i < 4; ++i) {
          float yv = (lnw[base + i] * ((y[d][rr * 4 + i] - u) * rstd) + lnb[base + i]) *
                     ONE_MINUS_LI;
          o.u[i] = f2bf(yv);
        }
        *reinterpret_cast<uint2*>(&yout[orow + base]) = o.v;
      }
  }
}

// ---------------- host ----------------
extern "C" void kernel_launch(void* const* d_in, const int* in_sizes, int n_in,
                              void* d_out, int out_size, void* d_ws, size_t ws_size,
                              hipStream_t stream) {
  (void)in_sizes; (void)n_in; (void)out_size; (void)ws_size;
  const float* q   = (const float*)d_in[0];
  const float* k   = (const float*)d_in[1];
  const float* v   = (const float*)d_in[2];
  const int* maskp = (const int*)d_in[3];
  const float* Wq1 = (const float*)d_in[4];
  const float* bq1 = (const float*)d_in[5];
  const float* Wq2 = (const float*)d_in[6];
  const float* bq2 = (const float*)d_in[7];
  const float* Wk1 = (const float*)d_in[8];
  const float* bk1 = (const float*)d_in[9];
  const float* Wk2 = (const float*)d_in[10];
  const float* bk2 = (const float*)d_in[11];
  const float* Wv  = (const float*)d_in[12];
  const float* bv  = (const float*)d_in[13];
  const float* Wc  = (const float*)d_in[14];
  const float* bc  = (const float*)d_in[15];
  const float* lnw = (const float*)d_in[16];
  const float* lnb = (const float*)d_in[17];
  const float* lq1 = (const float*)d_in[18];
  const float* lk1 = (const float*)d_in[19];
  const float* lq2 = (const float*)d_in[20];
  const float* lk2 = (const float*)d_in[21];

  char* ws = (char*)d_ws;
  u16* qb     = (u16*)(ws + 0);
  u16* kb     = (u16*)(ws + 8388608);
  u16* vb     = (u16*)(ws + 16777216);
  u16* Wq12T  = (u16*)(ws + 25165824);
  u16* Wk12T  = (u16*)(ws + 29360128);
  u16* WvT    = (u16*)(ws + 33554432);
  u16* WcT    = (u16*)(ws + 37748736);
  float* biasq = (float*)(ws + 41943040);
  float* biask = (float*)(ws + 41951232);
  u16* q1q2   = (u16*)(ws + 41959424);
  u16* k1k2   = (u16*)(ws + 58736640);
  u16* vvT    = (u16*)(ws + 75513856);
  u16* yb     = (u16*)(ws + 0);  // alias qb+kb (16MB; both dead before attention)

  const int NELEM = 2 * T_SEQ * 1024;  // 4,194,304

  cvt_bf16<<<4096, 256, 0, stream>>>(q, qb, NELEM);
  cvt_bf16<<<4096, 256, 0, stream>>>(k, kb, NELEM);
  cvt_bf16<<<4096, 256, 0, stream>>>(v, vb, NELEM);

  tcvt<<<dim3(32, 32), 256, 0, stream>>>(Wq1, Wq12T, 1024, 1024, 0);
  tcvt<<<dim3(32, 32), 256, 0, stream>>>(Wq2, Wq12T, 1024, 1024, 1024);
  tcvt<<<dim3(32, 32), 256, 0, stream>>>(Wk1, Wk12T, 1024, 1024, 0);
  tcvt<<<dim3(32, 32), 256, 0, stream>>>(Wk2, Wk12T, 1024, 1024, 1024);
  tcvt<<<dim3(64, 32), 256, 0, stream>>>(Wv, WvT, 1024, 2048, 0);
  tcvt<<<dim3(32, 64), 256, 0, stream>>>(Wc, WcT, 2048, 1024, 0);

  bias_concat<<<8, 256, 0, stream>>>(bq1, bq2, biasq);
  bias_concat<<<8, 256, 0, stream>>>(bk1, bk2, biask);

  gemm_bt<0><<<dim3(16, 32), 256, 0, stream>>>(qb, Wq12T, biasq, q1q2, 4096, 2048, 1024);
  gemm_bt<0><<<dim3(16, 32), 256, 0, stream>>>(kb, Wk12T, biask, k1k2, 4096, 2048, 1024);
  gemm_bt<1><<<dim3(16, 32), 256, 0, stream>>>(vb, WvT, bv, vvT, 4096, 2048, 1024);

  diffattn<<<1024, 256, 0, stream>>>(q1q2, k1k2, vvT, maskp,
                                     lq1, lk1, lq2, lk2, lnw, lnb, yb);

  gemm_bt<2><<<dim3(8, 32), 256, 0, stream>>>(yb, WcT, bc, d_out, 4096, 1024, 2048);
}

// Round 12
// 327.711 us; speedup vs baseline: 1.0762x; 1.0070x over previous
//
#include <hip/hip_runtime.h>
#include <hip/hip_bf16.h>
#include <stdint.h>

// MultiHeadDiffAttention — R12. R11: XCD swizzle worked (FETCH 139->25MB),
// diffattn 183us still sync-bound (3.4K cyc/iter vs ~500 busy). Changes:
// (1) KVBLK 32->64: half the barriers/key, 2 compute sub-tiles per stage;
// (2) tree-shaped tile-max (R11 had a serial 15-deep fmax chain);
// (3) q-proj and k-proj GEMMs merged into one M=8192 dispatch (ws layout is
//     contiguous: qb|kb, Wq12T|Wk12T, biasq|biask, q1q2|k1k2).
// B=2, T=2048, C=1024, H=16, HS=64.

#define T_SEQ 2048

typedef unsigned short u16;
typedef __attribute__((ext_vector_type(8))) short short8;
typedef __attribute__((ext_vector_type(4))) float f32x4;
typedef __attribute__((ext_vector_type(16))) float f32x16;

#define LAMBDA_INIT 0.35550906759096926f
#define ONE_MINUS_LI 0.6444909324090307f
#define SM_SCALE 0.125f
#define LOG2E 1.44269504f

__device__ __forceinline__ u16 f2bf(float f) {
  uint32_t u = __float_as_uint(f);
  return (u16)((u + 0x7FFFu + ((u >> 16) & 1u)) >> 16);
}
__device__ __forceinline__ float b2f(u16 u) {
  return __uint_as_float(((uint32_t)u) << 16);
}
__device__ __forceinline__ short8 ld8(const u16* p) {
  return *reinterpret_cast<const short8*>(p);
}
__device__ __forceinline__ void st8(u16* p, short8 v) {
  *reinterpret_cast<short8*>(p) = v;
}
__device__ __forceinline__ f32x4 mfma16(short8 a, short8 b, f32x4 c) {
  return __builtin_amdgcn_mfma_f32_16x16x32_bf16(a, b, c, 0, 0, 0);
}
__device__ __forceinline__ f32x16 mfma32(short8 a, short8 b, f32x16 c) {
  return __builtin_amdgcn_mfma_f32_32x32x16_bf16(a, b, c, 0, 0, 0);
}
__device__ __forceinline__ uint32_t cvtpk(float lo, float hi_) {
  uint32_t r;
  asm("v_cvt_pk_bf16_f32 %0, %1, %2" : "=v"(r) : "v"(lo), "v"(hi_));
  return r;
}

// ---------------- elementwise f32 -> bf16 ----------------
__global__ __launch_bounds__(256) void cvt_bf16(const float* __restrict__ in,
                                                u16* __restrict__ out, int n) {
  int i = (blockIdx.x * 256 + threadIdx.x) * 4;
  if (i >= n) return;
  float4 f = *reinterpret_cast<const float4*>(in + i);
  union { u16 u[4]; uint2 v; } pk;
  pk.u[0] = f2bf(f.x); pk.u[1] = f2bf(f.y); pk.u[2] = f2bf(f.z); pk.u[3] = f2bf(f.w);
  *reinterpret_cast<uint2*>(out + i) = pk.v;
}

// ------------- transpose + convert: W[K][N] f32 -> WT[N][K] bf16 -------------
__global__ __launch_bounds__(256) void tcvt(const float* __restrict__ W,
                                            u16* __restrict__ WT,
                                            int K, int N, int outRowOff) {
  __shared__ float tile[32][33];
  int n0 = blockIdx.x * 32, k0 = blockIdx.y * 32;
  int tx = threadIdx.x & 31, ty = threadIdx.x >> 5;  // ty 0..7
#pragma unroll
  for (int p = 0; p < 4; ++p)
    tile[ty + 8 * p][tx] = W[(size_t)(k0 + ty + 8 * p) * N + n0 + tx];
  __syncthreads();
#pragma unroll
  for (int p = 0; p < 4; ++p)
    WT[(size_t)(outRowOff + n0 + ty + 8 * p) * K + k0 + tx] = f2bf(tile[tx][ty + 8 * p]);
}

// ---------------- concat two 1024-float biases ----------------
__global__ __launch_bounds__(256) void bias_concat(const float* __restrict__ b1,
                                                   const float* __restrict__ b2,
                                                   float* __restrict__ out) {
  int i = blockIdx.x * 256 + threadIdx.x;  // 0..2047
  out[i] = (i < 1024) ? b1[i] : b2[i - 1024];
}

// ---------------- GEMM: C[M][N] = A[M][K] @ BT[N][K]^T + bias ----------------
// m97 geometry: 128x128 tile, BK=64, 4 waves, global_load_lds width 16.
// EPI 0: bf16 [M][N].  EPI 1: bf16 vvT ((b*2048+col)*2048 + t).  EPI 2: f32 [M][N].
// QK: fused q/k projection — rows >= 4096 switch BT/bias to the k-weights.
#define BM 128
#define BN 128
#define BK 64

template <int EPI, bool QK>
__global__ __launch_bounds__(256) void gemm_bt(const u16* __restrict__ A,
                                               const u16* __restrict__ BT,
                                               const float* __restrict__ bias,
                                               void* __restrict__ Cv,
                                               int M, int N, int K) {
  __shared__ __align__(16) u16 As[BM * BK];
  __shared__ __align__(16) u16 Bs[BN * BK];
  int t = threadIdx.x;
  int w = t >> 6, l = t & 63;
  int g = l >> 4, c16 = l & 15;
  int wr = w >> 1, wc = w & 1;
  size_t gm = (size_t)blockIdx.y * BM, gn = (size_t)blockIdx.x * BN;
  if (QK && gm >= 4096) {
    BT += (size_t)2048 * 1024;  // Wk12T follows Wq12T
    bias += 2048;               // biask follows biasq
  }

  f32x4 acc[4][4] = {};

  int srow = l >> 3;       // 0..7 (8 lanes per row, 8 elems each)
  int scol = (l & 7) * 8;  // 0..56
  const u16* Ag = A + (gm + w * 32 + srow) * (size_t)K + scol;
  const u16* Bg = BT + (gn + w * 32 + srow) * (size_t)K + scol;

  for (int kt = 0; kt < K; kt += BK) {
    __syncthreads();
#pragma unroll
    for (int c = 0; c < 4; ++c) {
      __builtin_amdgcn_global_load_lds(
          (const __attribute__((address_space(1))) void*)(Ag + (size_t)(c * 8) * K + kt),
          (__attribute__((address_space(3))) void*)&As[(w * 32 + c * 8) * BK], 16, 0, 0);
      __builtin_amdgcn_global_load_lds(
          (const __attribute__((address_space(1))) void*)(Bg + (size_t)(c * 8) * K + kt),
          (__attribute__((address_space(3))) void*)&Bs[(w * 32 + c * 8) * BK], 16, 0, 0);
    }
    __syncthreads();
#pragma unroll
    for (int kk = 0; kk < 2; ++kk) {
      short8 af[4], bf[4];
#pragma unroll
      for (int m = 0; m < 4; ++m)
        af[m] = *reinterpret_cast<const short8*>(
            &As[(wr * 64 + m * 16 + c16) * BK + kk * 32 + g * 8]);
#pragma unroll
      for (int n = 0; n < 4; ++n)
        bf[n] = *reinterpret_cast<const short8*>(
            &Bs[(wc * 64 + n * 16 + c16) * BK + kk * 32 + g * 8]);
#pragma unroll
      for (int m = 0; m < 4; ++m)
#pragma unroll
        for (int n = 0; n < 4; ++n)
          acc[m][n] = mfma16(af[m], bf[n], acc[m][n]);
    }
  }

#pragma unroll
  for (int m = 0; m < 4; ++m)
#pragma unroll
    for (int n = 0; n < 4; ++n) {
      int row0 = (int)gm + wr * 64 + m * 16 + g * 4;
      int col = (int)gn + wc * 64 + n * 16 + c16;
      float bz = bias[col];
      if (EPI == 0) {
        u16* C = (u16*)Cv;
#pragma unroll
        for (int r = 0; r < 4; ++r)
          C[(size_t)(row0 + r) * N + col] = f2bf(acc[m][n][r] + bz);
      } else if (EPI == 1) {
        u16* C = (u16*)Cv;
        int bb = row0 >> 11, tt = row0 & 2047;
        union { u16 u[4]; uint2 v; } pk;
#pragma unroll
        for (int r = 0; r < 4; ++r) pk.u[r] = f2bf(acc[m][n][r] + bz);
        *reinterpret_cast<uint2*>(&C[((size_t)(bb * 2048 + col)) * 2048 + tt]) = pk.v;
      } else {
        float* C = (float*)Cv;
#pragma unroll
        for (int r = 0; r < 4; ++r)
          C[(size_t)(row0 + r) * N + col] = acc[m][n][r] + bz;
      }
    }
}

// ---------------- differential flash attention + fused LN (32x32 swapped) ----
// grid 1024 (1D, XCD-swizzled), block 256 = 4 waves = 2 pairs.
// Pair p covers q-rows [xblk*64 + p*32, +32); wave stream s handles stream s+1.
// 64-key staged tiles (2 sub-tiles per barrier pair), R8-proven staging order.
#define KROW 72   // K/V row: 64 elems + 8 pad (144B)
#define YROW 72
__global__ __launch_bounds__(256, 3) void diffattn(
    const u16* __restrict__ q1q2, const u16* __restrict__ k1k2,
    const u16* __restrict__ vvT, const int* __restrict__ mask,
    const float* __restrict__ lq1, const float* __restrict__ lk1,
    const float* __restrict__ lq2, const float* __restrict__ lk2,
    const float* __restrict__ lnw, const float* __restrict__ lnb,
    u16* __restrict__ yout) {
  // Ks [2*64 rows][KROW] = 9216 elems ; Vs [128 rows][KROW] = 9216 elems
  __shared__ __align__(16) u16 smem[18432];
  u16* Ksm = smem;
  u16* Vsm = smem + 9216;
  u16* Ysm = smem;  // epilogue overlay

  int tid = threadIdx.x;
  int w = tid >> 6, l = tid & 63;
  int q = l & 31, hi = l >> 5;
  int pair = w >> 1, stream = w & 1;

  // XCD swizzle: same-(b,h) q-blocks land on one XCD -> K/V L2-local
  int id = blockIdx.x;            // 0..1023
  int j = id & 7, rest = id >> 3;
  int xblk = rest & 31, ygrp = rest >> 5;
  int bh = ygrp * 8 + j;
  int b = bh >> 4, h = bh & 15;
  int qr0 = xblk * 64 + pair * 32;

  // lambda
  float lm1 = lq1[h * 64 + l] * lk1[h * 64 + l];
  float lm2 = lq2[h * 64 + l] * lk2[h * 64 + l];
#pragma unroll
  for (int o = 32; o; o >>= 1) {
    lm1 += __shfl_xor(lm1, o);
    lm2 += __shfl_xor(lm2, o);
  }
  float lam = __expf(lm1) - __expf(lm2) + LAMBDA_INIT;

  int soff = stream * 1024;
  const u16* qrow = q1q2 + (size_t)(b * T_SEQ + qr0 + q) * 2048 + h * 64 + soff + hi * 8;
  short8 qf[4];
#pragma unroll
  for (int c = 0; c < 4; ++c) qf[c] = ld8(qrow + c * 16);

  // softmax in log2 domain; mask folds into scale (0 -> uniform softmax)
  float scale = (mask[b * T_SEQ + qr0 + q] == 0) ? 0.f : (SM_SCALE * LOG2E);

  float M = -INFINITY, L = 0.f;
  f32x16 acc[4] = {};

  // staging: thread t -> K row (t>>1) half (t&1), V row (t>>1) half (t&1)
  int srw = tid >> 1, shalf = tid & 1;
  int kstream = srw >> 6, kkey = srw & 63;
  const u16* srcK =
      k1k2 + (size_t)(b * T_SEQ + kkey) * 2048 + h * 64 + kstream * 1024 + shalf * 32;
  u16* dstK = &Ksm[srw * KROW + shalf * 32];
  const u16* srcV = vvT + ((size_t)(b * 16 + h) * 128 + srw) * 2048 + shalf * 32;
  u16* dstV = &Vsm[srw * KROW + shalf * 32];

  short8 kpre[4], vpre[4];
#pragma unroll
  for (int u = 0; u < 4; ++u) {
    kpre[u] = ld8(srcK + u * 8);
    vpre[u] = ld8(srcV + u * 8);
  }

  for (int kt = 0; kt < T_SEQ; kt += 64) {
    __syncthreads();  // previous tile's reads complete
#pragma unroll
    for (int u = 0; u < 4; ++u) {
      st8(dstK + u * 8, kpre[u]);
      st8(dstV + u * 8, vpre[u]);
    }
    __syncthreads();  // tile staged
    if (kt + 64 < T_SEQ) {  // prefetch next tile (consumed NEXT iter, across barrier)
      const u16* nk = srcK + (size_t)(kt + 64) * 2048;
      const u16* nv = srcV + (kt + 64);
#pragma unroll
      for (int u = 0; u < 4; ++u) {
        kpre[u] = ld8(nk + u * 8);
        vpre[u] = ld8(nv + u * 8);
      }
    }

#pragma unroll
    for (int st = 0; st < 2; ++st) {
      // K frags from LDS
      const u16* kbase = &Ksm[(stream * 64 + st * 32 + q) * KROW + hi * 8];
      short8 kf[4];
#pragma unroll
      for (int c = 0; c < 4; ++c) kf[c] = ld8(kbase + c * 16);

      f32x16 s = {};
#pragma unroll
      for (int c = 0; c < 4; ++c) s = mfma32(kf[c], qf[c], s);

      // tile max: max3-fusable tree + cross-half
      float m0 = fmaxf(fmaxf(s[0], s[1]), s[2]);
      float m1 = fmaxf(fmaxf(s[3], s[4]), s[5]);
      float m2 = fmaxf(fmaxf(s[6], s[7]), s[8]);
      float m3 = fmaxf(fmaxf(s[9], s[10]), s[11]);
      float m4 = fmaxf(fmaxf(s[12], s[13]), s[14]);
      float ma = fmaxf(fmaxf(m0, m1), m2);
      float mb = fmaxf(fmaxf(m3, m4), s[15]);
      float rm = fmaxf(ma, mb);
      rm = fmaxf(rm, __shfl_xor(rm, 32));
      float tm = rm * scale;

      // defer-max (log2 units: 11.5 ~ e^8)
      if (!__all(tm - M <= 11.5f)) {
        float Mn = fmaxf(M, tm);
        float a = exp2f(M - Mn);
        L *= a;
#pragma unroll
        for (int d = 0; d < 4; ++d) acc[d] *= a;
        M = Mn;
      }

      // p = exp2(s*scale - M) via fused fma
      float p[16];
#pragma unroll
      for (int r = 0; r < 16; ++r) p[r] = exp2f(__builtin_fmaf(s[r], scale, -M));
      float s8[8], s4[4];
#pragma unroll
      for (int i = 0; i < 8; ++i) s8[i] = p[i] + p[i + 8];
#pragma unroll
      for (int i = 0; i < 4; ++i) s4[i] = s8[i] + s8[i + 4];
      float ps = (s4[0] + s4[1]) + (s4[2] + s4[3]);
      ps += __shfl_xor(ps, 32);
      L += ps;

      // P^T B-frags in-register
      uint32_t a1 = cvtpk(p[0], p[1]), a2 = cvtpk(p[2], p[3]);
      uint32_t b1 = cvtpk(p[4], p[5]), b2 = cvtpk(p[6], p[7]);
      uint32_t c1 = cvtpk(p[8], p[9]), c2 = cvtpk(p[10], p[11]);
      uint32_t d1 = cvtpk(p[12], p[13]), d2 = cvtpk(p[14], p[15]);
      uint32_t sa1 = (uint32_t)__shfl_xor((int)a1, 32), sa2 = (uint32_t)__shfl_xor((int)a2, 32);
      uint32_t sb1 = (uint32_t)__shfl_xor((int)b1, 32), sb2 = (uint32_t)__shfl_xor((int)b2, 32);
      uint32_t sc1 = (uint32_t)__shfl_xor((int)c1, 32), sc2 = (uint32_t)__shfl_xor((int)c2, 32);
      uint32_t sd1 = (uint32_t)__shfl_xor((int)d1, 32), sd2 = (uint32_t)__shfl_xor((int)d2, 32);
      union { uint32_t u[4]; short8 s8v; } pu0, pu1;
      pu0.u[0] = hi ? sb1 : a1;  pu0.u[1] = hi ? sb2 : a2;
      pu0.u[2] = hi ? b1 : sa1;  pu0.u[3] = hi ? b2 : sa2;
      pu1.u[0] = hi ? sd1 : c1;  pu1.u[1] = hi ? sd2 : c2;
      pu1.u[2] = hi ? d1 : sc1;  pu1.u[3] = hi ? d2 : sc2;
      short8 pf0 = pu0.s8v, pf1 = pu1.s8v;

#pragma unroll
      for (int d = 0; d < 4; ++d) {
        const u16* vb0 = &Vsm[(d * 32 + q) * KROW + st * 32 + hi * 8];
        short8 vf0 = ld8(vb0);
        short8 vf1 = ld8(vb0 + 16);
        acc[d] = mfma32(vf0, pf0, acc[d]);
        acc[d] = mfma32(vf1, pf1, acc[d]);
      }
    }
  }

  float inv = 1.f / L;
  __syncthreads();  // staging dead -> Ysm overlay safe
  if (stream == 1) {
    u16* yrow = &Ysm[(pair * 64 + l) * YROW];
#pragma unroll
    for (int d = 0; d < 4; ++d) {
      union { uint32_t u[8]; short8 v[2]; } pk;
#pragma unroll
      for (int i = 0; i < 8; ++i)
        pk.u[i] = cvtpk(acc[d][2 * i] * inv, acc[d][2 * i + 1] * inv);
      st8(yrow + d * 16, pk.v[0]);
      st8(yrow + d * 16 + 8, pk.v[1]);
    }
  }
  __syncthreads();
  if (stream == 0) {
    const u16* yrow = &Ysm[(pair * 64 + l) * YROW];
    float y[4][16];
#pragma unroll
    for (int d = 0; d < 4; ++d) {
      short8 y2a = ld8(yrow + d * 16);
      short8 y2b = ld8(yrow + d * 16 + 8);
#pragma unroll
      for (int i = 0; i < 8; ++i) {
        y[d][i] = acc[d][i] * inv - lam * b2f((u16)y2a[i]);
        y[d][8 + i] = acc[d][8 + i] * inv - lam * b2f((u16)y2b[i]);
      }
    }
    float sm = 0.f;
#pragma unroll
    for (int d = 0; d < 4; ++d)
#pragma unroll
      for (int r = 0; r < 16; ++r) sm += y[d][r];
    sm += __shfl_xor(sm, 32);
    float u = sm * (1.f / 128.f);
    float var = 0.f;
#pragma unroll
    for (int d = 0; d < 4; ++d)
#pragma unroll
      for (int r = 0; r < 16; ++r) { float dd = y[d][r] - u; var += dd * dd; }
    var += __shfl_xor(var, 32);
    float rstd = rsqrtf(var * (1.f / 128.f) + 1e-12f);

    size_t orow = (size_t)(b * T_SEQ + qr0 + q) * 2048 + h * 128;
#pragma unroll
    for (int d = 0; d < 4; ++d)
#pragma unroll
      for (int rr = 0; rr < 4; ++rr) {
        int base = d * 32 + 8 * rr + 4 * hi;
        union { u16 u[4]; uint2 v; } o;
#pragma unroll
        for (int i = 0; i < 4; ++i) {
          float yv = (lnw[base + i] * ((y[d][rr * 4 + i] - u) * rstd) + lnb[base + i]) *
                     ONE_MINUS_LI;
          o.u[i] = f2bf(yv);
        }
        *reinterpret_cast<uint2*>(&yout[orow + base]) = o.v;
      }
  }
}

// ---------------- host ----------------
extern "C" void kernel_launch(void* const* d_in, const int* in_sizes, int n_in,
                              void* d_out, int out_size, void* d_ws, size_t ws_size,
                              hipStream_t stream) {
  (void)in_sizes; (void)n_in; (void)out_size; (void)ws_size;
  const float* q   = (const float*)d_in[0];
  const float* k   = (const float*)d_in[1];
  const float* v   = (const float*)d_in[2];
  const int* maskp = (const int*)d_in[3];
  const float* Wq1 = (const float*)d_in[4];
  const float* bq1 = (const float*)d_in[5];
  const float* Wq2 = (const float*)d_in[6];
  const float* bq2 = (const float*)d_in[7];
  const float* Wk1 = (const float*)d_in[8];
  const float* bk1 = (const float*)d_in[9];
  const float* Wk2 = (const float*)d_in[10];
  const float* bk2 = (const float*)d_in[11];
  const float* Wv  = (const float*)d_in[12];
  const float* bv  = (const float*)d_in[13];
  const float* Wc  = (const float*)d_in[14];
  const float* bc  = (const float*)d_in[15];
  const float* lnw = (const float*)d_in[16];
  const float* lnb = (const float*)d_in[17];
  const float* lq1 = (const float*)d_in[18];
  const float* lk1 = (const float*)d_in[19];
  const float* lq2 = (const float*)d_in[20];
  const float* lk2 = (const float*)d_in[21];

  char* ws = (char*)d_ws;
  u16* qb     = (u16*)(ws + 0);          // rows 0..4095 ; kb continues at 4096
  u16* kb     = (u16*)(ws + 8388608);
  u16* vb     = (u16*)(ws + 16777216);
  u16* Wq12T  = (u16*)(ws + 25165824);   // Wk12T contiguous after
  u16* Wk12T  = (u16*)(ws + 29360128);
  u16* WvT    = (u16*)(ws + 33554432);
  u16* WcT    = (u16*)(ws + 37748736);
  float* biasq = (float*)(ws + 41943040);  // biask contiguous after
  float* biask = (float*)(ws + 41951232);
  u16* q1q2   = (u16*)(ws + 41959424);   // k1k2 contiguous after
  u16* k1k2   = (u16*)(ws + 58736640);
  u16* vvT    = (u16*)(ws + 75513856);
  u16* yb     = (u16*)(ws + 0);  // alias qb+kb (16MB; both dead before attention)

  const int NELEM = 2 * T_SEQ * 1024;  // 4,194,304

  cvt_bf16<<<4096, 256, 0, stream>>>(q, qb, NELEM);
  cvt_bf16<<<4096, 256, 0, stream>>>(k, kb, NELEM);
  cvt_bf16<<<4096, 256, 0, stream>>>(v, vb, NELEM);

  tcvt<<<dim3(32, 32), 256, 0, stream>>>(Wq1, Wq12T, 1024, 1024, 0);
  tcvt<<<dim3(32, 32), 256, 0, stream>>>(Wq2, Wq12T, 1024, 1024, 1024);
  tcvt<<<dim3(32, 32), 256, 0, stream>>>(Wk1, Wk12T, 1024, 1024, 0);
  tcvt<<<dim3(32, 32), 256, 0, stream>>>(Wk2, Wk12T, 1024, 1024, 1024);
  tcvt<<<dim3(64, 32), 256, 0, stream>>>(Wv, WvT, 1024, 2048, 0);
  tcvt<<<dim3(32, 64), 256, 0, stream>>>(Wc, WcT, 2048, 1024, 0);

  bias_concat<<<8, 256, 0, stream>>>(bq1, bq2, biasq);
  bias_concat<<<8, 256, 0, stream>>>(bk1, bk2, biask);

  // fused q-proj + k-proj: M=8192 (qb|kb rows), BT/bias switch at row 4096
  gemm_bt<0, true><<<dim3(16, 64), 256, 0, stream>>>(qb, Wq12T, biasq, q1q2,
                                                     8192, 2048, 1024);
  gemm_bt<1, false><<<dim3(16, 32), 256, 0, stream>>>(vb, WvT, bv, vvT, 4096, 2048, 1024);

  diffattn<<<1024, 256, 0, stream>>>(q1q2, k1k2, vvT, maskp,
                                     lq1, lk1, lq2, lk2, lnw, lnb, yb);

  gemm_bt<2, false><<<dim3(8, 32), 256, 0, stream>>>(yb, WcT, bc, d_out, 4096, 1024, 2048);
}